// Round 3
// baseline (780.751 us; speedup 1.0000x reference)
//
#include <hip/hip_runtime.h>
#include <math.h>

#define ATT0_BLOCKS 256

typedef __attribute__((ext_vector_type(8))) short short8_t;
typedef __attribute__((ext_vector_type(4))) float f32x4;

// branch-free GELU: gelu(x) = 0.5x + 0.5|x|*erf(|x|/sqrt2), erf via A&S 7.1.26
// (|err| <= 1.5e-7, dwarfed by the bf16 rounding that follows)
__device__ __forceinline__ float gelu_f(float x) {
    float ax = fabsf(x) * 0.70710678118654752f;
    float t = __builtin_amdgcn_rcpf(fmaf(ax, 0.3275911f, 1.0f));
    float p = fmaf(t, 1.061405429f, -1.453152027f);
    p = fmaf(t, p, 1.421413741f);
    p = fmaf(t, p, -0.284496736f);
    p = fmaf(t, p, 0.254829592f);
    p = p * t;
    float e = __expf(-ax * ax);
    float erfv = 1.0f - p * e;          // erf(|x|/sqrt2) >= 0
    return fmaf(0.5f * copysignf(erfv, x), x, 0.5f * x);
}

__device__ __forceinline__ float pe_val(int pos, int j, int D) {
    int i2 = j & ~1;
    float freq = expf(-9.210340371976184f * (float)i2 / (float)D); // -ln(10000)
    float arg = (float)pos * freq;
    return (j & 1) ? cosf(arg) : sinf(arg);
}

__device__ __forceinline__ unsigned short f2bf(float f) {
    unsigned u = __float_as_uint(f);
    return (unsigned short)((u + 0x7fffu + ((u >> 16) & 1u)) >> 16);
}

// swizzled bf16 LDS tile: rows of 256 bf16 (512 B), byte ^= (row&7)<<4
__device__ __forceinline__ void st_bf(unsigned short* X2, int row, int col, unsigned short v) {
    int byte = (row * 512 + col * 2) ^ ((row & 7) << 4);
    *(unsigned short*)((char*)X2 + byte) = v;
}
__device__ __forceinline__ short8_t ldA(const unsigned short* X2, int m, int ks, int l) {
    int byte = (m * 512 + ks * 64 + ((l >> 4) << 4)) ^ ((m & 7) << 4);
    return *(const short8_t*)((const char*)X2 + byte);
}

// ---------------------------------------------------------------------------
// Pack fp32 weight [256 x (CT*16)] into fragment-linear bf16
// ---------------------------------------------------------------------------
__global__ __launch_bounds__(256) void k_pack(const float* __restrict__ src,
                                              unsigned short* __restrict__ dst,
                                              int CT, int ld, int row0)
{
    int idx = blockIdx.x * 256 + threadIdx.x;
    if (idx >= 4096 * CT) return;
    int i = idx & 7, l = (idx >> 3) & 63, fc = idx >> 9;
    int c = fc % CT, ks = fc / CT;
    int k = ks * 32 + ((l >> 4) << 3) + i;
    int col = c * 16 + (l & 15);
    dst[idx] = f2bf(src[(size_t)(row0 + k) * ld + col]);
}

// ---------------------------------------------------------------------------
// MFMA stage: wave covers 2 row-tiles (32 rows) x NT col-tiles from ct0
// ---------------------------------------------------------------------------
template <int NT>
__device__ __forceinline__ void mm_frag(const unsigned short* X2,
                                        const unsigned short* __restrict__ Wp,
                                        int CT, int ct0, int l, f32x4 acc[2][NT])
{
    #pragma unroll
    for (int rt = 0; rt < 2; ++rt)
        #pragma unroll
        for (int t = 0; t < NT; ++t)
            acc[rt][t] = (f32x4){0.f, 0.f, 0.f, 0.f};
    #pragma unroll
    for (int ks = 0; ks < 8; ++ks) {
        short8_t a0 = ldA(X2, (l & 15), ks, l);
        short8_t a1 = ldA(X2, 16 + (l & 15), ks, l);
        #pragma unroll
        for (int t = 0; t < NT; ++t) {
            short8_t b = *(const short8_t*)(Wp + (size_t)((ks * CT + ct0 + t) * 64 + l) * 8);
            acc[0][t] = __builtin_amdgcn_mfma_f32_16x16x32_bf16(a0, b, acc[0][t], 0, 0, 0);
            acc[1][t] = __builtin_amdgcn_mfma_f32_16x16x32_bf16(a1, b, acc[1][t], 0, 0, 0);
        }
    }
}

// ---------------------------------------------------------------------------
// LN over fragment registers -> swizzled bf16 X2.
// Internal barrier; caller must barrier AFTER (before X2 is read) and, if X2
// was being read just before, barrier BEFORE the call.
// ---------------------------------------------------------------------------
__device__ __forceinline__ void ln_frag(const f32x4 res[2][4], unsigned short* X2,
                                        float* SP, const float* __restrict__ g,
                                        const float* __restrict__ bvec, int wid, int l)
{
    int l15 = l & 15, gq = l >> 4;
    float mv[8], rs[8];
    #pragma unroll
    for (int rt = 0; rt < 2; ++rt)
        #pragma unroll
        for (int rr = 0; rr < 4; ++rr) {
            int idx = rt * 4 + rr;
            float s = 0.f, q = 0.f;
            #pragma unroll
            for (int t = 0; t < 4; ++t) { float v = res[rt][t][rr]; s += v; q = fmaf(v, v, q); }
            #pragma unroll
            for (int off = 1; off < 16; off <<= 1) { s += __shfl_xor(s, off); q += __shfl_xor(q, off); }
            mv[idx] = s; rs[idx] = q;
        }
    if (l15 == 0) {
        #pragma unroll
        for (int rt = 0; rt < 2; ++rt)
            #pragma unroll
            for (int rr = 0; rr < 4; ++rr) {
                int row = rt * 16 + gq * 4 + rr;
                SP[(wid * 32 + row) * 2 + 0] = mv[rt * 4 + rr];
                SP[(wid * 32 + row) * 2 + 1] = rs[rt * 4 + rr];
            }
    }
    __syncthreads();
    #pragma unroll
    for (int rt = 0; rt < 2; ++rt)
        #pragma unroll
        for (int rr = 0; rr < 4; ++rr) {
            int idx = rt * 4 + rr, row = rt * 16 + gq * 4 + rr;
            float s = 0.f, q = 0.f;
            #pragma unroll
            for (int w = 0; w < 4; ++w) { s += SP[(w * 32 + row) * 2]; q += SP[(w * 32 + row) * 2 + 1]; }
            float mean = s * (1.f / 256.f);
            float var = q * (1.f / 256.f) - mean * mean;
            mv[idx] = mean; rs[idx] = rsqrtf(var + 1e-5f);
        }
    #pragma unroll
    for (int t = 0; t < 4; ++t) {
        int col = (wid * 4 + t) * 16 + l15;
        float gg = g[col], bb = bvec[col];
        #pragma unroll
        for (int rt = 0; rt < 2; ++rt)
            #pragma unroll
            for (int rr = 0; rr < 4; ++rr) {
                int row = rt * 16 + gq * 4 + rr;
                float v = (res[rt][t][rr] - mv[rt * 4 + rr]) * rs[rt * 4 + rr] * gg + bb;
                st_bf(X2, row, col, f2bf(v));
            }
    }
}

// ---------------------------------------------------------------------------
// K1: tiny setup — q rows, bias rows, c2/c3 constant vectors
// ---------------------------------------------------------------------------
__global__ __launch_bounds__(256) void k_small(
    const float* __restrict__ qW1, const float* __restrict__ qb1,
    const float* __restrict__ qW2, const float* __restrict__ qb2,
    const float* __restrict__ bW1, const float* __restrict__ bb1,
    const float* __restrict__ bW2, const float* __restrict__ bb2,
    const float* __restrict__ m2W1, const float* __restrict__ m2b1,
    const float* __restrict__ m3W1, const float* __restrict__ m3b1,
    float* __restrict__ q01, float* __restrict__ ball,
    float* __restrict__ c2, float* __restrict__ c3)
{
    __shared__ float pe[256];
    __shared__ float h[256];
    int b = blockIdx.x, tid = threadIdx.x;
    if (b < 11) {
        int pos = (b < 2) ? b : (b - 2);
        if (tid < 64) pe[tid] = pe_val(pos, tid, 64);
        __syncthreads();
        const float* W1 = (b < 2) ? qW1 : bW1;
        const float* b1 = (b < 2) ? qb1 : bb1;
        const float* W2 = (b < 2) ? qW2 : bW2;
        const float* b2 = (b < 2) ? qb2 : bb2;
        float acc = b1[tid];
        for (int d = 0; d < 64; ++d) acc += pe[d] * W1[d * 256 + tid];
        h[tid] = gelu_f(acc);
        __syncthreads();
        float acc2 = b2[tid];
        for (int d = 0; d < 256; ++d) acc2 += h[d] * W2[d * 256 + tid];
        if (b < 2) q01[b * 256 + tid] = acc2;
        else ball[(b - 2) * 256 + tid] = acc2;
    } else {
        int pos; const float* W1; const float* b1; float* dst;
        if (b < 13) { pos = b - 11; W1 = m2W1; b1 = m2b1; dst = c2 + pos * 256; }
        else        { pos = b - 13; W1 = m3W1; b1 = m3b1; dst = c3 + pos * 256; }
        pe[tid] = pe_val(pos, tid, 256);
        __syncthreads();
        float acc = b1[tid];
        for (int d = 0; d < 256; ++d) acc += pe[d] * W1[(256 + d) * 256 + tid];
        dst[tid] = acc;
    }
}

// ---------------------------------------------------------------------------
// K2: x1 = x + mlp1(ln(x)); v = x1@vW+vb -> global; logits from kW accs
// ---------------------------------------------------------------------------
__global__ __launch_bounds__(256, 3) void k_node(
    const float* __restrict__ x,
    const unsigned short* __restrict__ m1W1p, const float* __restrict__ m1b1,
    const unsigned short* __restrict__ m1W2p, const float* __restrict__ m1b2,
    const float* __restrict__ n1g, const float* __restrict__ n1b,
    const unsigned short* __restrict__ kWp, const float* __restrict__ kb,
    const unsigned short* __restrict__ vWp, const float* __restrict__ vb,
    const float* __restrict__ q01,
    float* __restrict__ v_out, float* __restrict__ lg0, float* __restrict__ lg1, int N)
{
    __shared__ __align__(16) unsigned short X2[32 * 256];
    __shared__ float SP[256];

    int tid = threadIdx.x;
    int l = tid & 63, wid = tid >> 6, l15 = l & 15, gq = l >> 4;
    int row0 = blockIdx.x * 32;

    int col_[4];
    #pragma unroll
    for (int t = 0; t < 4; ++t) col_[t] = (wid * 4 + t) * 16 + l15;

    f32x4 res[2][4], acc[2][4];
    // load x fragments
    #pragma unroll
    for (int rt = 0; rt < 2; ++rt)
        #pragma unroll
        for (int rr = 0; rr < 4; ++rr) {
            int n = row0 + rt * 16 + gq * 4 + rr;
            #pragma unroll
            for (int t = 0; t < 4; ++t)
                res[rt][t][rr] = (n < N) ? x[(size_t)n * 256 + col_[t]] : 0.f;
        }
    ln_frag(res, X2, SP, n1g, n1b, wid, l);
    __syncthreads();

    // mlp1 stage 1
    mm_frag<4>(X2, m1W1p, 16, wid * 4, l, acc);
    __syncthreads();
    #pragma unroll
    for (int t = 0; t < 4; ++t) {
        float bb = m1b1[col_[t]];
        #pragma unroll
        for (int rt = 0; rt < 2; ++rt)
            #pragma unroll
            for (int rr = 0; rr < 4; ++rr)
                st_bf(X2, rt * 16 + gq * 4 + rr, col_[t], f2bf(gelu_f(acc[rt][t][rr] + bb)));
    }
    __syncthreads();
    // mlp1 stage 2: res += h @ m1W2 + b
    mm_frag<4>(X2, m1W2p, 16, wid * 4, l, acc);
    #pragma unroll
    for (int t = 0; t < 4; ++t) {
        float bb = m1b2[col_[t]];
        #pragma unroll
        for (int rt = 0; rt < 2; ++rt)
            #pragma unroll
            for (int rr = 0; rr < 4; ++rr)
                res[rt][t][rr] += acc[rt][t][rr] + bb;
    }
    __syncthreads();
    // x1 -> X2 bf16
    #pragma unroll
    for (int t = 0; t < 4; ++t)
        #pragma unroll
        for (int rt = 0; rt < 2; ++rt)
            #pragma unroll
            for (int rr = 0; rr < 4; ++rr)
                st_bf(X2, rt * 16 + gq * 4 + rr, col_[t], f2bf(res[rt][t][rr]));
    __syncthreads();

    // k projection: logits straight from accumulators
    {
        f32x4 acck[2][8];
        mm_frag<8>(X2, kWp, 32, wid * 8, l, acck);
        int which = wid >> 1;
        int h0 = (wid & 1) * 4;
        float lp[2][4][4];
        #pragma unroll
        for (int rt = 0; rt < 2; ++rt)
            #pragma unroll
            for (int r = 0; r < 4; ++r)
                #pragma unroll
                for (int hl = 0; hl < 4; ++hl) lp[rt][r][hl] = 0.f;
        #pragma unroll
        for (int t = 0; t < 8; ++t) {
            int d = ((t & 1) << 4) | l15;
            int h = h0 + (t >> 1);
            int col = (which * 16 + (wid & 1) * 8 + t) * 16 + l15;
            float qv = q01[which * 256 + h * 32 + d];
            float kbv = kb[col];
            #pragma unroll
            for (int rt = 0; rt < 2; ++rt)
                #pragma unroll
                for (int r = 0; r < 4; ++r)
                    lp[rt][r][t >> 1] += qv * (acck[rt][t][r] + kbv);
        }
        #pragma unroll
        for (int off = 1; off < 16; off <<= 1)
            #pragma unroll
            for (int rt = 0; rt < 2; ++rt)
                #pragma unroll
                for (int r = 0; r < 4; ++r)
                    #pragma unroll
                    for (int hl = 0; hl < 4; ++hl)
                        lp[rt][r][hl] += __shfl_xor(lp[rt][r][hl], off);
        if (l15 == 0) {
            float* dst = which ? lg1 : lg0;
            #pragma unroll
            for (int rt = 0; rt < 2; ++rt)
                #pragma unroll
                for (int r = 0; r < 4; ++r) {
                    int n = row0 + rt * 16 + gq * 4 + r;
                    if (n < N)
                        #pragma unroll
                        for (int hl = 0; hl < 4; ++hl)
                            dst[(size_t)n * 8 + h0 + hl] = lp[rt][r][hl] * 0.17677669529663687f;
                }
        }
    }
    // v projection -> global
    mm_frag<4>(X2, vWp, 16, wid * 4, l, acc);
    #pragma unroll
    for (int t = 0; t < 4; ++t) {
        float bb = vb[col_[t]];
        #pragma unroll
        for (int rt = 0; rt < 2; ++rt)
            #pragma unroll
            for (int rr = 0; rr < 4; ++rr) {
                int n = row0 + rt * 16 + gq * 4 + rr;
                if (n < N) v_out[(size_t)n * 256 + col_[t]] = acc[rt][t][rr] + bb;
            }
    }
}

// ---------------------------------------------------------------------------
// K3: order-0 attention partials (deterministic)
// ---------------------------------------------------------------------------
__global__ __launch_bounds__(256) void k_att0_partial(
    const float* __restrict__ lg0, const float* __restrict__ v, int N,
    float* __restrict__ part)
{
    int tid = threadIdx.x, b = blockIdx.x;
    int chunk = (N + ATT0_BLOCKS - 1) / ATT0_BLOCKS;
    int n0 = b * chunk, n1 = min(N, n0 + chunk);
    int h = tid >> 5;
    float acc = 0.f, dacc = 0.f;
    for (int n = n0; n < n1; ++n) {
        float e = expf(lg0[(size_t)n * 8 + h]);
        acc += e * v[(size_t)n * 256 + tid];
        if ((tid & 31) == 0) dacc += e;
    }
    part[b * 264 + tid] = acc;
    if ((tid & 31) == 0) part[b * 264 + 256 + h] = dacc;
}

__global__ __launch_bounds__(256) void k_att0_final(
    const float* __restrict__ part,
    const float* __restrict__ m2W1, const float* __restrict__ m2W2,
    const float* __restrict__ m2b2,
    const float* __restrict__ n2g, const float* __restrict__ n2b,
    const float* __restrict__ c2, float* __restrict__ att0f)
{
    __shared__ float L[256], H[256], red[16], dsh[8];
    int tid = threadIdx.x;
    float s = 0.f;
    for (int b = 0; b < ATT0_BLOCKS; ++b) s += part[b * 264 + tid];
    if (tid < 8) {
        float d = 0.f;
        for (int b = 0; b < ATT0_BLOCKS; ++b) d += part[b * 264 + 256 + tid];
        dsh[tid] = d;
    }
    __syncthreads();
    float a = s / dsh[tid >> 5];
    float ss = a, sq = a * a;
    for (int off = 32; off; off >>= 1) { ss += __shfl_down(ss, off); sq += __shfl_down(sq, off); }
    int lane = tid & 63, wid = tid >> 6;
    if (lane == 0) { red[wid] = ss; red[4 + wid] = sq; }
    __syncthreads();
    if (tid == 0) {
        float S1 = red[0] + red[1] + red[2] + red[3];
        float S2 = red[4] + red[5] + red[6] + red[7];
        float mean = S1 / 256.f, var = S2 / 256.f - mean * mean;
        red[8] = mean; red[9] = rsqrtf(var + 1e-5f);
    }
    __syncthreads();
    L[tid] = (a - red[8]) * red[9] * n2g[tid] + n2b[tid];
    __syncthreads();
    float acc = c2[tid];
    for (int d = 0; d < 256; ++d) acc += L[d] * m2W1[d * 256 + tid];
    H[tid] = gelu_f(acc);
    __syncthreads();
    float acc2 = m2b2[tid];
    for (int d = 0; d < 256; ++d) acc2 += H[d] * m2W2[d * 256 + tid];
    att0f[tid] = a + acc2;
}

// ---------------------------------------------------------------------------
// K5/K6: [optional fused att1_e gather] + blk2 + att0 + blk3 + bias
// GATHER=true: in = v[N][256], gathers 32 edges/block; else in = rows [M][256]
// ---------------------------------------------------------------------------
template <bool GATHER>
__global__ __launch_bounds__(256, 4) void k_blk23(
    const float* __restrict__ in, float* __restrict__ outp, int M,
    const int* __restrict__ node_idx, const float* __restrict__ lg1,
    const unsigned short* __restrict__ m2W1p, const unsigned short* __restrict__ m2W2p,
    const float* __restrict__ m2b2,
    const unsigned short* __restrict__ m3W1p, const unsigned short* __restrict__ m3W2p,
    const float* __restrict__ m3b2,
    const float* __restrict__ n2g, const float* __restrict__ n2b,
    const float* __restrict__ n3g, const float* __restrict__ n3b,
    const float* __restrict__ c2row, const float* __restrict__ c3tab,
    const float* __restrict__ att0f, const float* __restrict__ ball,
    const int* __restrict__ orders)
{
    // LDS: [AF fp32 32x258 | X2 aliases AF] + W8 + nid + ords + SP (gather)
    //      [X2 16KB] + SP (node)
    __shared__ __align__(16) char smem[GATHER ? (33024 + 8192 + 1024 + 128 + 1024)
                                              : (16384 + 1024)];
    float* AF = (float*)smem;
    unsigned short* X2 = (unsigned short*)smem;
    float* W8 = (float*)(smem + 33024);
    int* nidS = (int*)(smem + 33024 + 8192);
    int* ordsS = (int*)(smem + 33024 + 8192 + 1024);
    float* SP = (float*)(smem + (GATHER ? (33024 + 8192 + 1024 + 128) : 16384));

    int tid = threadIdx.x;
    int l = tid & 63, wid = tid >> 6, l15 = l & 15, gq = l >> 4;
    int row0 = blockIdx.x * 32;

    int col_[4];
    #pragma unroll
    for (int t = 0; t < 4; ++t) col_[t] = (wid * 4 + t) * 16 + l15;

    f32x4 res[2][4], acc[2][4];
    int ordv[8];

    if (GATHER) {
        // G1: nid + per-(e,i) logit rows
        int e = tid >> 3, i = tid & 7;
        int ge = row0 + e;
        int nd = (ge < M) ? node_idx[(size_t)ge * 8 + i] : 0;
        nidS[tid] = nd;
        if (tid < 32) ordsS[tid] = (row0 + tid < M) ? orders[row0 + tid] : 1;
        {
            const float4* lp4 = (const float4*)(lg1 + (size_t)nd * 8);
            ((float4*)W8)[(e * 8 + i) * 2] = lp4[0];
            ((float4*)W8)[(e * 8 + i) * 2 + 1] = lp4[1];
        }
        __syncthreads();
        // G2: softmax over the 8 incident nodes, per (e,h)
        {
            int e2 = tid >> 3, h = tid & 7;
            float m = -1e30f;
            #pragma unroll
            for (int i2 = 0; i2 < 8; ++i2) m = fmaxf(m, W8[(e2 * 8 + i2) * 8 + h]);
            float w[8], den = 0.f;
            #pragma unroll
            for (int i2 = 0; i2 < 8; ++i2) { w[i2] = __expf(W8[(e2 * 8 + i2) * 8 + h] - m); den += w[i2]; }
            float rd = 1.0f / den;
            #pragma unroll
            for (int i2 = 0; i2 < 8; ++i2) W8[(e2 * 8 + i2) * 8 + h] = w[i2] * rd;
        }
        __syncthreads();
        // G3: weighted gather, thread = column (coalesced 1KB v-row reads)
        {
            int h = tid >> 5;
            #pragma unroll 4
            for (int e3 = 0; e3 < 32; ++e3) {
                float s = 0.f;
                #pragma unroll
                for (int i3 = 0; i3 < 8; ++i3)
                    s += W8[(e3 * 8 + i3) * 8 + h] * in[(size_t)nidS[e3 * 8 + i3] * 256 + tid];
                AF[e3 * 258 + tid] = s;
            }
        }
        __syncthreads();
        // G4: fragment load (AF dead after; X2 aliasing is safe past ln_frag's barrier)
        #pragma unroll
        for (int rt = 0; rt < 2; ++rt)
            #pragma unroll
            for (int rr = 0; rr < 4; ++rr) {
                int row = rt * 16 + gq * 4 + rr;
                #pragma unroll
                for (int t = 0; t < 4; ++t)
                    res[rt][t][rr] = AF[row * 258 + col_[t]];
                ordv[rt * 4 + rr] = ordsS[row];
            }
    } else {
        #pragma unroll
        for (int rt = 0; rt < 2; ++rt)
            #pragma unroll
            for (int rr = 0; rr < 4; ++rr) {
                int n = row0 + rt * 16 + gq * 4 + rr;
                #pragma unroll
                for (int t = 0; t < 4; ++t)
                    res[rt][t][rr] = (n < M) ? in[(size_t)n * 256 + col_[t]] : 0.f;
                ordv[rt * 4 + rr] = 1;
            }
    }

    // ---- blk2 ----
    ln_frag(res, X2, SP, n2g, n2b, wid, l);
    __syncthreads();
    mm_frag<4>(X2, m2W1p, 16, wid * 4, l, acc);
    __syncthreads();
    #pragma unroll
    for (int t = 0; t < 4; ++t) {
        float bb = c2row[col_[t]];
        #pragma unroll
        for (int rt = 0; rt < 2; ++rt)
            #pragma unroll
            for (int rr = 0; rr < 4; ++rr)
                st_bf(X2, rt * 16 + gq * 4 + rr, col_[t], f2bf(gelu_f(acc[rt][t][rr] + bb)));
    }
    __syncthreads();
    mm_frag<4>(X2, m2W2p, 16, wid * 4, l, acc);
    #pragma unroll
    for (int t = 0; t < 4; ++t) {
        float bb = m2b2[col_[t]] + att0f[col_[t]];
        #pragma unroll
        for (int rt = 0; rt < 2; ++rt)
            #pragma unroll
            for (int rr = 0; rr < 4; ++rr)
                res[rt][t][rr] += acc[rt][t][rr] + bb;
    }
    __syncthreads();      // all stage-B X2 reads complete before LN2 rewrites X2
    // ---- blk3 ----
    ln_frag(res, X2, SP, n3g, n3b, wid, l);
    __syncthreads();
    mm_frag<4>(X2, m3W1p, 16, wid * 4, l, acc);
    __syncthreads();
    #pragma unroll
    for (int t = 0; t < 4; ++t) {
        #pragma unroll
        for (int rt = 0; rt < 2; ++rt)
            #pragma unroll
            for (int rr = 0; rr < 4; ++rr) {
                float bb = c3tab[ordv[rt * 4 + rr] * 256 + col_[t]];
                st_bf(X2, rt * 16 + gq * 4 + rr, col_[t], f2bf(gelu_f(acc[rt][t][rr] + bb)));
            }
    }
    __syncthreads();
    mm_frag<4>(X2, m3W2p, 16, wid * 4, l, acc);
    #pragma unroll
    for (int t = 0; t < 4; ++t) {
        float bb = m3b2[col_[t]];
        #pragma unroll
        for (int rt = 0; rt < 2; ++rt)
            #pragma unroll
            for (int rr = 0; rr < 4; ++rr) {
                int row = rt * 16 + gq * 4 + rr;
                int n = row0 + row;
                if (n < M)
                    outp[(size_t)n * 256 + col_[t]] = res[rt][t][rr] + acc[rt][t][rr] + bb
                                                      + ball[ordv[rt * 4 + rr] * 256 + col_[t]];
            }
    }
}

extern "C" void kernel_launch(void* const* d_in, const int* in_sizes, int n_in,
                              void* d_out, int out_size, void* d_ws, size_t ws_size,
                              hipStream_t stream)
{
    const float* x          = (const float*)d_in[0];
    const int*   node_idx   = (const int*)d_in[1];
    const int*   edge_orders= (const int*)d_in[3];
    const float* qW1 = (const float*)d_in[4];
    const float* qb1 = (const float*)d_in[5];
    const float* qW2 = (const float*)d_in[6];
    const float* qb2 = (const float*)d_in[7];
    const float* kW  = (const float*)d_in[8];
    const float* kb  = (const float*)d_in[9];
    const float* vW  = (const float*)d_in[10];
    const float* vb  = (const float*)d_in[11];
    const float* m1W1= (const float*)d_in[12];
    const float* m1b1= (const float*)d_in[13];
    const float* m1W2= (const float*)d_in[14];
    const float* m1b2= (const float*)d_in[15];
    const float* m2W1= (const float*)d_in[16];
    const float* m2b1= (const float*)d_in[17];
    const float* m2W2= (const float*)d_in[18];
    const float* m2b2= (const float*)d_in[19];
    const float* m3W1= (const float*)d_in[20];
    const float* m3b1= (const float*)d_in[21];
    const float* m3W2= (const float*)d_in[22];
    const float* m3b2= (const float*)d_in[23];
    const float* n1g = (const float*)d_in[24];
    const float* n1b = (const float*)d_in[25];
    const float* n2g = (const float*)d_in[26];
    const float* n2b = (const float*)d_in[27];
    const float* n3g = (const float*)d_in[28];
    const float* n3b = (const float*)d_in[29];
    const float* bW1 = (const float*)d_in[30];
    const float* bb1 = (const float*)d_in[31];
    const float* bW2 = (const float*)d_in[32];
    const float* bb2 = (const float*)d_in[33];

    int N = in_sizes[0] / 256;
    int E = in_sizes[3];

    float* ws    = (float*)d_ws;
    float* q01   = ws;               // 512
    float* ball  = ws + 512;         // 9*256
    float* c2    = ws + 2816;        // 2*256
    float* c3    = ws + 3328;        // 9*256
    float* att0f = ws + 5632;        // 256
    float* part  = ws + 5888;        // 256*264 -> end 73472
    float* lg0   = ws + 73472;       // N*8
    float* lg1   = lg0 + (size_t)N * 8;
    unsigned short* pk = (unsigned short*)(ws + 873472);
    unsigned short* m1W1p = pk;
    unsigned short* m1W2p = pk + 65536;
    unsigned short* kWp   = pk + 131072;
    unsigned short* vWp   = pk + 262144;
    unsigned short* m2W1p = pk + 327680;
    unsigned short* m2W2p = pk + 393216;
    unsigned short* m3W1p = pk + 458752;
    unsigned short* m3W2p = pk + 524288;

    float* v_out = (float*)d_out;                       // [N,256]: v, then x_v
    float* out_e = (float*)d_out + (size_t)N * 256;     // [E,256]: x_e

    k_pack<<<16 * 16, 256, 0, stream>>>(m1W1, m1W1p, 16, 256, 0);
    k_pack<<<16 * 16, 256, 0, stream>>>(m1W2, m1W2p, 16, 256, 0);
    k_pack<<<16 * 32, 256, 0, stream>>>(kW,   kWp,   32, 512, 0);
    k_pack<<<16 * 16, 256, 0, stream>>>(vW,   vWp,   16, 256, 0);
    k_pack<<<16 * 16, 256, 0, stream>>>(m2W1, m2W1p, 16, 256, 0);
    k_pack<<<16 * 16, 256, 0, stream>>>(m2W2, m2W2p, 16, 256, 0);
    k_pack<<<16 * 16, 256, 0, stream>>>(m3W1, m3W1p, 16, 256, 0);
    k_pack<<<16 * 16, 256, 0, stream>>>(m3W2, m3W2p, 16, 256, 0);

    k_small<<<22, 256, 0, stream>>>(qW1, qb1, qW2, qb2, bW1, bb1, bW2, bb2,
                                    m2W1, m2b1, m3W1, m3b1, q01, ball, c2, c3);
    k_node<<<(N + 31) / 32, 256, 0, stream>>>(x, m1W1p, m1b1, m1W2p, m1b2, n1g, n1b,
                                              kWp, kb, vWp, vb, q01, v_out, lg0, lg1, N);
    k_att0_partial<<<ATT0_BLOCKS, 256, 0, stream>>>(lg0, v_out, N, part);
    k_att0_final<<<1, 256, 0, stream>>>(part, m2W1, m2W2, m2b2, n2g, n2b, c2, att0f);
    // edge kernel FIRST (gathers from v_out) then node kernel (in-place on v_out)
    k_blk23<true><<<(E + 31) / 32, 256, 0, stream>>>(v_out, out_e, E, node_idx, lg1,
        m2W1p, m2W2p, m2b2, m3W1p, m3W2p, m3b2, n2g, n2b, n3g, n3b,
        c2 + 256, c3, att0f, ball, edge_orders);
    k_blk23<false><<<(N + 31) / 32, 256, 0, stream>>>(v_out, v_out, N, nullptr, nullptr,
        m2W1p, m2W2p, m2b2, m3W1p, m3W2p, m3b2, n2g, n2b, n3g, n3b,
        c2 + 256, c3, att0f, ball, nullptr);
}